// Round 9
// baseline (227.145 us; speedup 1.0000x reference)
//
#include <hip/hip_runtime.h>
#include <hip/hip_bf16.h>
#include <math.h>

// B=16, H=64, W=64, C=64 -> N=4096 pixels/batch, M=1024 pooled cells.
#define NB 16
#define NPIX 4096
#define MPOOL 1024

// DIAGNOSTIC ROUND: kernels internally repeat their (idempotent) bodies so each
// exceeds the ~44 µs fill dispatches and surfaces full PMC counters for the first
// time. Output is bit-identical to single-rep. CONV_REPS*conv ~52-60 µs,
// ATTN_REPS*attn ~69-75 µs -> both in top-5.
#define CONV_REPS 4
#define ATTN_REPS 3

typedef __attribute__((ext_vector_type(8))) short bf16x8;  // 8 bf16 (4 VGPRs)
typedef __attribute__((ext_vector_type(4))) float f32x4;   // MFMA C/D frag

#define LOG2E 1.44269504088896340736f

__device__ inline unsigned short f2bf(float f) {
    __hip_bfloat16 h = __float2bfloat16(f);
    return *reinterpret_cast<unsigned short*>(&h);
}

#if defined(__has_builtin)
#if __has_builtin(__builtin_amdgcn_cvt_pk_bf16_f32)
#define HAVE_PK_BF16 1
#endif
#endif
__device__ inline unsigned pack_bf16(float a, float b) {
#ifdef HAVE_PK_BF16
    typedef __bf16 bf16v2 __attribute__((ext_vector_type(2)));
    bf16v2 v = __builtin_amdgcn_cvt_pk_bf16_f32(a, b);
    unsigned u;
    __builtin_memcpy(&u, &v, 4);
    return u;
#else
    unsigned ua = __float_as_uint(a) + 0x8000u;
    unsigned ub = __float_as_uint(b) + 0x8000u;
    return __builtin_amdgcn_perm(ua, ub, 0x03020706u);
#endif
}

// Workspace layout (u16 elements from start of ws):
//   theta_bf @0        [16*4096*8]   (PRE-SCALED by log2e for exp2-softmax)
//   phi_bf   @524288   [16*1024*8]
//   gT_bf    @655360   [16*32*1024]
//   woT_bf   @1179648  [64*32]       (SN'd w_o, transposed [co][k])

__device__ inline float wave_sum64(float v) {
    #pragma unroll
    for (int off = 32; off >= 1; off >>= 1) v += __shfl_xor(v, off);
    return v;
}

// Wave-local spectral norm (one power-iteration step, matches reference).
// Whole wave must enter. Returns 1/sigma (wave-uniform).
template<int D, int COUT>
__device__ float sn_inv_sigma(const float* __restrict__ w, const float* __restrict__ u) {
    const int lane = threadIdx.x & 63;
    float vi = 0.f;
    if (lane < D) {
        #pragma unroll 8
        for (int j = 0; j < COUT; ++j) vi += w[lane * COUT + j] * u[j];
    }
    float nn = wave_sum64(vi * vi);
    vi *= 1.0f / (sqrtf(nn) + 1e-12f);

    float u2 = 0.f;
    #pragma unroll 8
    for (int i = 0; i < D; ++i) {
        float vv = __shfl(vi, i);                   // all lanes execute the shuffle
        if (lane < COUT) u2 += w[i * COUT + lane] * vv;
    }
    float nn2 = wave_sum64(u2 * u2);
    u2 *= 1.0f / (sqrtf(nn2) + 1e-12f);

    float ti = 0.f;
    #pragma unroll 8
    for (int j = 0; j < COUT; ++j) {
        float uv = __shfl(u2, j);
        if (lane < D) ti += w[lane * COUT + j] * uv;
    }
    float sig = wave_sum64(vi * ti);
    return 1.0f / sig;
}

// ---------------- fused SN + conv (round-3 body, wrapped in rep loop) ----------------
__global__ __launch_bounds__(256) void conv_all_kernel(const float* __restrict__ x,
                                                       const float* __restrict__ w_theta, const float* __restrict__ u_theta,
                                                       const float* __restrict__ w_phi,   const float* __restrict__ u_phi,
                                                       const float* __restrict__ w_g,     const float* __restrict__ u_g,
                                                       const float* __restrict__ w_o,     const float* __restrict__ u_o,
                                                       unsigned short* __restrict__ theta_bf,
                                                       unsigned short* __restrict__ phi_bf,
                                                       unsigned short* __restrict__ gT_bf,
                                                       unsigned short* __restrict__ woT_bf) {
    __shared__ unsigned short sx[128 * 72];  // x strip bf16, row pad 72 (reused for out-staging)
    __shared__ unsigned short sw[48 * 72];   // W^T [col][k], pad 72
    __shared__ float s_inv[3];

    const int tid  = threadIdx.x;
    const int b    = blockIdx.x >> 5;
    const int hp   = blockIdx.x & 31;        // rows 2hp, 2hp+1
    const int h0   = hp * 2;
    const int wv   = tid >> 6;
    const int lane = tid & 63;
    const int quad = lane >> 4;
    const int lcol = lane & 15;
    const int w0   = wv * 16;

    for (int rep = 0; rep < CONV_REPS; ++rep) {
    // stage x strip: 8192 floats = 2048 float4 -> 8 iters
    const float4* xb4 = (const float4*)(x + (((size_t)b * NPIX) + h0 * 64) * 64);
    #pragma unroll
    for (int it = 0; it < 8; ++it) {
        const int li = tid + it * 256;
        float4 v = xb4[li];
        const int px = li >> 4, c4 = li & 15;
        uint2 pk;
        pk.x = pack_bf16(v.x, v.y);
        pk.y = pack_bf16(v.z, v.w);
        *(uint2*)(&sx[px * 72 + c4 * 4]) = pk;
    }
    // per-wave spectral norm (redundant across blocks; weights tiny + L2-hot)
    if (wv == 0)      { float iv = sn_inv_sigma<64, 8>(w_theta, u_theta); if (lane == 0) s_inv[0] = iv; }
    else if (wv == 1) { float iv = sn_inv_sigma<64, 8>(w_phi,   u_phi);   if (lane == 0) s_inv[1] = iv; }
    else if (wv == 2) { float iv = sn_inv_sigma<64, 32>(w_g,    u_g);     if (lane == 0) s_inv[2] = iv; }
    else if (blockIdx.x == 0) {
        // block 0 wave 3: w_o spectral norm -> woT_bf[n*32+k] = bf16(w_o[k][n]/sigma)
        float iv = sn_inv_sigma<32, 64>(w_o, u_o);
        for (int idx = lane; idx < 64 * 32; idx += 64) {
            const int n = idx >> 5, k = idx & 31;
            woT_bf[idx] = f2bf(w_o[k * 64 + n] * iv);
        }
    }
    __syncthreads();

    // fill sw: cols 0-7 theta, 8-15 phi, 16-47 g; sw[col][k] = bf16(w[k][col]/sigma)
    {
        const float i0 = s_inv[0], i1 = s_inv[1], i2 = s_inv[2];
        #pragma unroll
        for (int it = 0; it < 12; ++it) {
            const int idx = tid + it * 256;      // 0..3071; col is wave-uniform per iter
            const int col = idx >> 6, k = idx & 63;
            float wvf, inv;
            if (col < 8)       { wvf = w_theta[k * 8 + col];        inv = i0; }
            else if (col < 16) { wvf = w_phi[k * 8 + (col - 8)];    inv = i1; }
            else               { wvf = w_g[k * 32 + (col - 16)];    inv = i2; }
            sw[col * 72 + k] = f2bf(wvf * inv);
        }
    }
    __syncthreads();

    bf16x8 a[2][2];
    #pragma unroll
    for (int hh = 0; hh < 2; ++hh)
        #pragma unroll
        for (int kc = 0; kc < 2; ++kc)
            a[hh][kc] = *(const bf16x8*)(sx + (hh * 64 + w0 + lcol) * 72 + kc * 32 + quad * 8);

    f32x4 acc[2][3];
    #pragma unroll
    for (int ct = 0; ct < 3; ++ct) {
        bf16x8 b0 = *(const bf16x8*)(sw + (ct * 16 + lcol) * 72 + 0 * 32 + quad * 8);
        bf16x8 b1 = *(const bf16x8*)(sw + (ct * 16 + lcol) * 72 + 1 * 32 + quad * 8);
        #pragma unroll
        for (int hh = 0; hh < 2; ++hh) {
            f32x4 c = __builtin_amdgcn_mfma_f32_16x16x32_bf16(a[hh][0], b0, (f32x4)0.0f, 0, 0, 0);
            acc[hh][ct] = __builtin_amdgcn_mfma_f32_16x16x32_bf16(a[hh][1], b1, c, 0, 0, 0);
        }
    }
    __syncthreads();   // all LDS reads of sx/sw done -> safe to overlay staging tiles

    // ---- stage outputs in LDS (overlaid on sx), then write coalesced ----
    unsigned short* th = sx;
    unsigned short* ph = sx + 1024;
    unsigned short* gg = sx + 1280;
    const int ml = (w0 >> 1) + quad * 2;     // local pooled m within block, 0..31
    if (lcol < 8) {
        #pragma unroll
        for (int hh = 0; hh < 2; ++hh) {
            const int pix = hh * 64 + w0 + quad * 4;
            #pragma unroll
            for (int r = 0; r < 4; ++r)
                th[(pix + r) * 8 + lcol] = f2bf(acc[hh][0][r] * LOG2E);  // pre-scale for exp2
        }
    } else {
        #pragma unroll
        for (int r2 = 0; r2 < 2; ++r2) {
            float pe = fmaxf(fmaxf(acc[0][0][2 * r2], acc[0][0][2 * r2 + 1]),
                             fmaxf(acc[1][0][2 * r2], acc[1][0][2 * r2 + 1]));
            ph[(ml + r2) * 8 + (lcol - 8)] = f2bf(pe);
        }
    }
    #pragma unroll
    for (int ct = 1; ct < 3; ++ct) {
        const int cg = (ct - 1) * 16 + lcol;
        #pragma unroll
        for (int r2 = 0; r2 < 2; ++r2) {
            float pe = fmaxf(fmaxf(acc[0][ct][2 * r2], acc[0][ct][2 * r2 + 1]),
                             fmaxf(acc[1][ct][2 * r2], acc[1][ct][2 * r2 + 1]));
            gg[cg * 32 + ml + r2] = f2bf(pe);
        }
    }
    __syncthreads();

    // coalesced global writes: 288 float4 total (th 128, ph 32, gg 128)
    const float4* sv4 = (const float4*)sx;
    float4* th4 = (float4*)(theta_bf + ((size_t)b * NPIX + hp * 128) * 8);
    float4* ph4 = (float4*)(phi_bf + ((size_t)b * MPOOL + hp * 32) * 8);
    for (int idx = tid; idx < 288; idx += 256) {
        float4 v = sv4[idx];
        if (idx < 128) {
            th4[idx] = v;
        } else if (idx < 160) {
            ph4[idx - 128] = v;
        } else {
            const int gi = idx - 160;            // 0..127
            const int ch = gi >> 2, part = gi & 3;
            *(float4*)(gT_bf + ((size_t)b * 32 + ch) * MPOOL + hp * 32 + part * 8) = v;
        }
    }
    __syncthreads();   // rep boundary: all sv4 reads done before next rep's staging
    }
}

// ---------------- attn v3 (round-6 body, wrapped in rep loop) ----------------
__global__ __launch_bounds__(1024) void attn_kernel(const unsigned short* __restrict__ theta_bf,
                                                    const unsigned short* __restrict__ phi_bf,
                                                    const unsigned short* __restrict__ gT_bf,
                                                    const unsigned short* __restrict__ woT_bf,
                                                    const float* __restrict__ x,
                                                    const float* __restrict__ gamma,
                                                    float* __restrict__ out) {
    __shared__ unsigned short sphi[MPOOL * 8];    // 16 KB
    __shared__ unsigned short sg[32 * 264];       // 16.9 KB: gT tile [32 ch][256 m + 8 pad]
    __shared__ unsigned short sP[16][16 * 72];    // 36.9 KB: per-wave P 16q x 64m, stride 72

    const int tid  = threadIdx.x;
    const int b    = blockIdx.x >> 4;
    const int qb   = blockIdx.x & 15;
    const int w    = tid >> 6;                    // wave 0..15
    const int lane = tid & 63;
    const int quad = lane >> 4;
    const int lcol = lane & 15;

    for (int rep = 0; rep < ATTN_REPS; ++rep) {
    // stage phi[b] (16 KB): 1024 float4, one per thread
    {
        const float4* src = (const float4*)(phi_bf + (size_t)b * (MPOOL * 8));
        ((float4*)sphi)[tid] = src[tid];
    }
    // stage gT tile 0: thread (r=tid>>5, seg=tid&31) copies m seg*8..+7 (one float4)
    const unsigned short* gTb = gT_bf + (size_t)b * (32 * MPOOL);
    const int gr = tid >> 5, gseg = tid & 31;
    {
        *(float4*)(&sg[gr * 264 + gseg * 8]) =
            *(const float4*)(gTb + gr * MPOOL + gseg * 8);
    }
    // theta frag (K=8 real, zero-pad k>=8 -> quads 1-3 zero); used as B operand.
    const int q0w = qb * 256 + w * 16;
    bf16x8 tfrag = (bf16x8)(short)0;
    if (quad == 0)
        tfrag = *(const bf16x8*)(theta_bf + ((size_t)b * NPIX + q0w + lcol) * 8);
    __syncthreads();

    f32x4 olo = (f32x4)0.0f, ohi = (f32x4)0.0f;
    float ls = 0.f;
    unsigned short* sPw = sP[w];

    for (int t = 0; t < 4; ++t) {
        float4 pre;
        if (t < 3)
            pre = *(const float4*)(gTb + gr * MPOOL + (t + 1) * 256 + gseg * 8);
        for (int cb = 0; cb < 4; ++cb) {
            const int m0 = t * 256 + cb * 64;
            f32x4 s[4];
            #pragma unroll
            for (int sc = 0; sc < 4; ++sc) {
                bf16x8 pf = *(const bf16x8*)(sphi + (size_t)(m0 + sc * 16 + lcol) * 8);
                // S^T tile: D[row=m (quad*4+r within sc*16)][col=q (lcol)]
                s[sc] = __builtin_amdgcn_mfma_f32_16x16x32_bf16(pf, tfrag, (f32x4)0.0f, 0, 0, 0);
            }
            #pragma unroll
            for (int sc = 0; sc < 4; ++sc) {
                float e0 = exp2f(s[sc][0]);
                float e1 = exp2f(s[sc][1]);
                float e2 = exp2f(s[sc][2]);
                float e3 = exp2f(s[sc][3]);
                ls += (e0 + e1) + (e2 + e3);
                uint2 pk2;
                pk2.x = pack_bf16(e0, e1);
                pk2.y = pack_bf16(e2, e3);
                *(uint2*)(sPw + lcol * 72 + sc * 16 + quad * 4) = pk2;
            }
            asm volatile("s_waitcnt lgkmcnt(0)" ::: "memory");
            #pragma unroll
            for (int pkk = 0; pkk < 2; ++pkk) {
                bf16x8 afrag = *(const bf16x8*)(sPw + lcol * 72 + pkk * 32 + quad * 8);
                bf16x8 bg0 = *(const bf16x8*)(sg + lcol * 264 + cb * 64 + pkk * 32 + quad * 8);
                olo = __builtin_amdgcn_mfma_f32_16x16x32_bf16(afrag, bg0, olo, 0, 0, 0);
                bf16x8 bg1 = *(const bf16x8*)(sg + (16 + lcol) * 264 + cb * 64 + pkk * 32 + quad * 8);
                ohi = __builtin_amdgcn_mfma_f32_16x16x32_bf16(afrag, bg1, ohi, 0, 0, 0);
            }
        }
        if (t < 3) {
            __syncthreads();   // all waves done reading tile t
            *(float4*)(&sg[gr * 264 + gseg * 8]) = pre;
            __syncthreads();   // tile t+1 visible
        }
    }

    // softmax denominator for q = lcol: sum over quads (lanes lcol+16k)
    ls += __shfl_xor(ls, 16);
    ls += __shfl_xor(ls, 32);
    const float invq = 1.0f / ls;

    // ag (UNNORMALIZED) -> per-wave LDS round-trip: [q][ch], stride 40
    #pragma unroll
    for (int r = 0; r < 4; ++r) {
        sPw[(quad * 4 + r) * 40 + lcol]      = f2bf(olo[r]);
        sPw[(quad * 4 + r) * 40 + 16 + lcol] = f2bf(ohi[r]);
    }
    asm volatile("s_waitcnt lgkmcnt(0)" ::: "memory");
    bf16x8 agf = *(const bf16x8*)(sPw + lcol * 40 + quad * 8);  // B[k=ch][n=q=lcol]

    const float gmi = gamma[0] * invq;
    const size_t pixbase = ((size_t)b * NPIX + q0w + lcol) * 64;
    #pragma unroll
    for (int ct = 0; ct < 4; ++ct) {
        // A[co][k] straight from L2 (woT is 4 KB, shared by all blocks)
        bf16x8 wa = *(const bf16x8*)(woT_bf + (ct * 16 + lcol) * 32 + quad * 8);
        f32x4 oc = __builtin_amdgcn_mfma_f32_16x16x32_bf16(wa, agf, (f32x4)0.0f, 0, 0, 0);
        const float4 xv = *(const float4*)(x + pixbase + ct * 16 + quad * 4);
        float4 ov;
        ov.x = xv.x + gmi * oc[0];
        ov.y = xv.y + gmi * oc[1];
        ov.z = xv.z + gmi * oc[2];
        ov.w = xv.w + gmi * oc[3];
        *(float4*)(out + pixbase + ct * 16 + quad * 4) = ov;
    }
    __syncthreads();   // rep boundary: sP/sg reads done before next rep's staging
    }
}

extern "C" void kernel_launch(void* const* d_in, const int* in_sizes, int n_in,
                              void* d_out, int out_size, void* d_ws, size_t ws_size,
                              hipStream_t stream) {
    const float* x       = (const float*)d_in[0];
    const float* w_theta = (const float*)d_in[1];
    const float* u_theta = (const float*)d_in[2];
    const float* w_phi   = (const float*)d_in[3];
    const float* u_phi   = (const float*)d_in[4];
    const float* w_g     = (const float*)d_in[5];
    const float* u_g     = (const float*)d_in[6];
    const float* w_o     = (const float*)d_in[7];
    const float* u_o     = (const float*)d_in[8];
    const float* gamma   = (const float*)d_in[9];
    float* out = (float*)d_out;

    unsigned short* u16base  = (unsigned short*)d_ws;
    unsigned short* theta_bf = u16base;                  // 524288
    unsigned short* phi_bf   = u16base + 524288;         // 131072
    unsigned short* gT_bf    = u16base + 655360;         // 524288
    unsigned short* woT_bf   = u16base + 1179648;        // 2048

    conv_all_kernel<<<512, 256, 0, stream>>>(x, w_theta, u_theta, w_phi, u_phi, w_g, u_g,
                                             w_o, u_o, theta_bf, phi_bf, gT_bf, woT_bf);
    attn_kernel<<<256, 1024, 0, stream>>>(theta_bf, phi_bf, gT_bf, woT_bf, x, gamma, out);
}

// Round 10
// 131.693 us; speedup vs baseline: 1.7248x; 1.7248x over previous
//
#include <hip/hip_runtime.h>
#include <hip/hip_bf16.h>
#include <math.h>

// B=16, H=64, W=64, C=64 -> N=4096 pixels/batch, M=1024 pooled cells.
#define NB 16
#define NPIX 4096
#define MPOOL 1024

typedef __attribute__((ext_vector_type(8))) short bf16x8;  // 8 bf16 (4 VGPRs)
typedef __attribute__((ext_vector_type(4))) float f32x4;   // MFMA C/D frag

#define LOG2E 1.44269504088896340736f

__device__ inline unsigned short f2bf(float f) {
    __hip_bfloat16 h = __float2bfloat16(f);
    return *reinterpret_cast<unsigned short*>(&h);
}

#if defined(__has_builtin)
#if __has_builtin(__builtin_amdgcn_cvt_pk_bf16_f32)
#define HAVE_PK_BF16 1
#endif
#if __has_builtin(__builtin_amdgcn_exp2f)
#define EXP2_HW(x) __builtin_amdgcn_exp2f(x)   // bare v_exp_f32, no libm wrapper
#endif
#endif
#ifndef EXP2_HW
#define EXP2_HW(x) exp2f(x)
#endif

__device__ inline unsigned pack_bf16(float a, float b) {
#ifdef HAVE_PK_BF16
    typedef __bf16 bf16v2 __attribute__((ext_vector_type(2)));
    bf16v2 v = __builtin_amdgcn_cvt_pk_bf16_f32(a, b);
    unsigned u;
    __builtin_memcpy(&u, &v, 4);
    return u;
#else
    unsigned ua = __float_as_uint(a) + 0x8000u;
    unsigned ub = __float_as_uint(b) + 0x8000u;
    return __builtin_amdgcn_perm(ua, ub, 0x03020706u);
#endif
}

// Workspace layout (u16 elements from start of ws):
//   theta_bf @0        [16*4096*8]   (PRE-SCALED by log2e for exp2-softmax)
//   phi_bf   @524288   [16*1024*8]
//   gT_bf    @655360   [16*32*1024]
//   woT_bf   @1179648  [64*32]       (SN'd w_o, transposed [co][k])

__device__ inline float wave_sum64(float v) {
    #pragma unroll
    for (int off = 32; off >= 1; off >>= 1) v += __shfl_xor(v, off);
    return v;
}

// Wave-local spectral norm (one power-iteration step, matches reference).
template<int D, int COUT>
__device__ float sn_inv_sigma(const float* __restrict__ w, const float* __restrict__ u) {
    const int lane = threadIdx.x & 63;
    float vi = 0.f;
    if (lane < D) {
        #pragma unroll 8
        for (int j = 0; j < COUT; ++j) vi += w[lane * COUT + j] * u[j];
    }
    float nn = wave_sum64(vi * vi);
    vi *= 1.0f / (sqrtf(nn) + 1e-12f);

    float u2 = 0.f;
    #pragma unroll 8
    for (int i = 0; i < D; ++i) {
        float vv = __shfl(vi, i);
        if (lane < COUT) u2 += w[i * COUT + lane] * vv;
    }
    float nn2 = wave_sum64(u2 * u2);
    u2 *= 1.0f / (sqrtf(nn2) + 1e-12f);

    float ti = 0.f;
    #pragma unroll 8
    for (int j = 0; j < COUT; ++j) {
        float uv = __shfl(u2, j);
        if (lane < D) ti += w[lane * COUT + j] * uv;
    }
    float sig = wave_sum64(vi * ti);
    return 1.0f / sig;
}

// ---------------- fused SN + conv (byte-identical to verified round-3/6 kernel) ----------------
__global__ __launch_bounds__(256) void conv_all_kernel(const float* __restrict__ x,
                                                       const float* __restrict__ w_theta, const float* __restrict__ u_theta,
                                                       const float* __restrict__ w_phi,   const float* __restrict__ u_phi,
                                                       const float* __restrict__ w_g,     const float* __restrict__ u_g,
                                                       const float* __restrict__ w_o,     const float* __restrict__ u_o,
                                                       unsigned short* __restrict__ theta_bf,
                                                       unsigned short* __restrict__ phi_bf,
                                                       unsigned short* __restrict__ gT_bf,
                                                       unsigned short* __restrict__ woT_bf) {
    __shared__ unsigned short sx[128 * 72];
    __shared__ unsigned short sw[48 * 72];
    __shared__ float s_inv[3];

    const int tid  = threadIdx.x;
    const int b    = blockIdx.x >> 5;
    const int hp   = blockIdx.x & 31;
    const int h0   = hp * 2;
    const int wv   = tid >> 6;
    const int lane = tid & 63;
    const int quad = lane >> 4;
    const int lcol = lane & 15;
    const int w0   = wv * 16;

    const float4* xb4 = (const float4*)(x + (((size_t)b * NPIX) + h0 * 64) * 64);
    #pragma unroll
    for (int it = 0; it < 8; ++it) {
        const int li = tid + it * 256;
        float4 v = xb4[li];
        const int px = li >> 4, c4 = li & 15;
        uint2 pk;
        pk.x = pack_bf16(v.x, v.y);
        pk.y = pack_bf16(v.z, v.w);
        *(uint2*)(&sx[px * 72 + c4 * 4]) = pk;
    }
    if (wv == 0)      { float iv = sn_inv_sigma<64, 8>(w_theta, u_theta); if (lane == 0) s_inv[0] = iv; }
    else if (wv == 1) { float iv = sn_inv_sigma<64, 8>(w_phi,   u_phi);   if (lane == 0) s_inv[1] = iv; }
    else if (wv == 2) { float iv = sn_inv_sigma<64, 32>(w_g,    u_g);     if (lane == 0) s_inv[2] = iv; }
    else if (blockIdx.x == 0) {
        float iv = sn_inv_sigma<32, 64>(w_o, u_o);
        for (int idx = lane; idx < 64 * 32; idx += 64) {
            const int n = idx >> 5, k = idx & 31;
            woT_bf[idx] = f2bf(w_o[k * 64 + n] * iv);
        }
    }
    __syncthreads();

    {
        const float i0 = s_inv[0], i1 = s_inv[1], i2 = s_inv[2];
        #pragma unroll
        for (int it = 0; it < 12; ++it) {
            const int idx = tid + it * 256;
            const int col = idx >> 6, k = idx & 63;
            float wvf, inv;
            if (col < 8)       { wvf = w_theta[k * 8 + col];        inv = i0; }
            else if (col < 16) { wvf = w_phi[k * 8 + (col - 8)];    inv = i1; }
            else               { wvf = w_g[k * 32 + (col - 16)];    inv = i2; }
            sw[col * 72 + k] = f2bf(wvf * inv);
        }
    }
    __syncthreads();

    bf16x8 a[2][2];
    #pragma unroll
    for (int hh = 0; hh < 2; ++hh)
        #pragma unroll
        for (int kc = 0; kc < 2; ++kc)
            a[hh][kc] = *(const bf16x8*)(sx + (hh * 64 + w0 + lcol) * 72 + kc * 32 + quad * 8);

    f32x4 acc[2][3];
    #pragma unroll
    for (int ct = 0; ct < 3; ++ct) {
        bf16x8 b0 = *(const bf16x8*)(sw + (ct * 16 + lcol) * 72 + 0 * 32 + quad * 8);
        bf16x8 b1 = *(const bf16x8*)(sw + (ct * 16 + lcol) * 72 + 1 * 32 + quad * 8);
        #pragma unroll
        for (int hh = 0; hh < 2; ++hh) {
            f32x4 c = __builtin_amdgcn_mfma_f32_16x16x32_bf16(a[hh][0], b0, (f32x4)0.0f, 0, 0, 0);
            acc[hh][ct] = __builtin_amdgcn_mfma_f32_16x16x32_bf16(a[hh][1], b1, c, 0, 0, 0);
        }
    }
    __syncthreads();

    unsigned short* th = sx;
    unsigned short* ph = sx + 1024;
    unsigned short* gg = sx + 1280;
    const int ml = (w0 >> 1) + quad * 2;
    if (lcol < 8) {
        #pragma unroll
        for (int hh = 0; hh < 2; ++hh) {
            const int pix = hh * 64 + w0 + quad * 4;
            #pragma unroll
            for (int r = 0; r < 4; ++r)
                th[(pix + r) * 8 + lcol] = f2bf(acc[hh][0][r] * LOG2E);
        }
    } else {
        #pragma unroll
        for (int r2 = 0; r2 < 2; ++r2) {
            float pe = fmaxf(fmaxf(acc[0][0][2 * r2], acc[0][0][2 * r2 + 1]),
                             fmaxf(acc[1][0][2 * r2], acc[1][0][2 * r2 + 1]));
            ph[(ml + r2) * 8 + (lcol - 8)] = f2bf(pe);
        }
    }
    #pragma unroll
    for (int ct = 1; ct < 3; ++ct) {
        const int cg = (ct - 1) * 16 + lcol;
        #pragma unroll
        for (int r2 = 0; r2 < 2; ++r2) {
            float pe = fmaxf(fmaxf(acc[0][ct][2 * r2], acc[0][ct][2 * r2 + 1]),
                             fmaxf(acc[1][ct][2 * r2], acc[1][ct][2 * r2 + 1]));
            gg[cg * 32 + ml + r2] = f2bf(pe);
        }
    }
    __syncthreads();

    const float4* sv4 = (const float4*)sx;
    float4* th4 = (float4*)(theta_bf + ((size_t)b * NPIX + hp * 128) * 8);
    float4* ph4 = (float4*)(phi_bf + ((size_t)b * MPOOL + hp * 32) * 8);
    for (int idx = tid; idx < 288; idx += 256) {
        float4 v = sv4[idx];
        if (idx < 128) {
            th4[idx] = v;
        } else if (idx < 160) {
            ph4[idx - 128] = v;
        } else {
            const int gi = idx - 160;
            const int ch = gi >> 2, part = gi & 3;
            *(float4*)(gT_bf + ((size_t)b * 32 + ch) * MPOOL + hp * 32 + part * 8) = v;
        }
    }
}

// ---------------- attn v4: R6 structure, VALU diet + XOR-swizzled LDS ----------------
// Counter-driven (R9: VALUBusy 63%, MfmaUtil 13%, 7.9M bank-conflict cycles):
//  (1) bare v_exp_f32 via builtin (exp2f was libm);
//  (2) all sP/sg LDS offsets precomputed, loop-invariant;
//  (3) 16B-slot XOR swizzle (slot ^= row&7) on sP and sg, write+read sides,
//      killing the 8-way (lcol+quad)-class conflicts.
__global__ __launch_bounds__(1024) void attn_kernel(const unsigned short* __restrict__ theta_bf,
                                                    const unsigned short* __restrict__ phi_bf,
                                                    const unsigned short* __restrict__ gT_bf,
                                                    const unsigned short* __restrict__ woT_bf,
                                                    const float* __restrict__ x,
                                                    const float* __restrict__ gamma,
                                                    float* __restrict__ out) {
    __shared__ unsigned short sphi[MPOOL * 8];    // 16 KB
    __shared__ unsigned short sg[32 * 264];       // 16.9 KB [ch][256m slots swizzled]
    __shared__ unsigned short sP[16][16 * 72];    // 36.9 KB per-wave P, slots swizzled

    const int tid  = threadIdx.x;
    const int b    = blockIdx.x >> 4;
    const int qb   = blockIdx.x & 15;
    const int w    = tid >> 6;
    const int lane = tid & 63;
    const int quad = lane >> 4;
    const int lcol = lane & 15;
    const int swl  = lcol & 7;                    // XOR key (row&7; rows are lcol / 16+lcol)

    // stage phi[b]
    {
        const float4* src = (const float4*)(phi_bf + (size_t)b * (MPOOL * 8));
        ((float4*)sphi)[tid] = src[tid];
    }
    // stage gT tile 0, swizzled: row gr, 16B slot gseg -> slot gseg^(gr&7)
    const unsigned short* gTb = gT_bf + (size_t)b * (32 * MPOOL);
    const int gr = tid >> 5, gseg = tid & 31;
    const int gdst = gr * 264 + ((gseg ^ (gr & 7)) * 8);   // u16 idx, loop-invariant
    {
        *(float4*)(&sg[gdst]) = *(const float4*)(gTb + gr * MPOOL + gseg * 8);
    }
    // theta frag
    const int q0w = qb * 256 + w * 16;
    bf16x8 tfrag = (bf16x8)(short)0;
    if (quad == 0)
        tfrag = *(const bf16x8*)(theta_bf + ((size_t)b * NPIX + q0w + lcol) * 8);

    // ---- precomputed LDS offsets (all loop-invariant, live in SGPR/VGPR) ----
    unsigned short* sPw = sP[w];
    // sP writes (8B ds_write per sc): slot = sc*2+(quad>>1), half = quad&1
    int pw[4];
    #pragma unroll
    for (int sc = 0; sc < 4; ++sc)
        pw[sc] = lcol * 72 + (((sc * 2 + (quad >> 1)) ^ swl) << 3) + ((quad & 1) << 2);
    // sP reads (16B): slot = pkk*4+quad
    const int pr0 = lcol * 72 + (((0 + quad) ^ swl) << 3);
    const int pr1 = lcol * 72 + (((4 + quad) ^ swl) << 3);
    // sg reads (16B): slot = cb*8 + pkk*4 + quad -> cb passes through high bits
    const int gr0 = ((0 + quad) ^ swl) << 3;
    const int gr1 = ((4 + quad) ^ swl) << 3;
    const unsigned short* sg_lo = sg + lcol * 264;
    const unsigned short* sg_hi = sg + (16 + lcol) * 264;
    __syncthreads();

    f32x4 olo = (f32x4)0.0f, ohi = (f32x4)0.0f;
    float ls = 0.f;

    for (int t = 0; t < 4; ++t) {
        float4 pre;
        if (t < 3)
            pre = *(const float4*)(gTb + gr * MPOOL + (t + 1) * 256 + gseg * 8);
        for (int cb = 0; cb < 4; ++cb) {
            const int m0 = t * 256 + cb * 64;
            f32x4 s[4];
            #pragma unroll
            for (int sc = 0; sc < 4; ++sc) {
                bf16x8 pf = *(const bf16x8*)(sphi + (size_t)(m0 + sc * 16 + lcol) * 8);
                s[sc] = __builtin_amdgcn_mfma_f32_16x16x32_bf16(pf, tfrag, (f32x4)0.0f, 0, 0, 0);
            }
            #pragma unroll
            for (int sc = 0; sc < 4; ++sc) {
                float e0 = EXP2_HW(s[sc][0]);
                float e1 = EXP2_HW(s[sc][1]);
                float e2 = EXP2_HW(s[sc][2]);
                float e3 = EXP2_HW(s[sc][3]);
                ls += (e0 + e1) + (e2 + e3);
                uint2 pk2;
                pk2.x = pack_bf16(e0, e1);
                pk2.y = pack_bf16(e2, e3);
                *(uint2*)(sPw + pw[sc]) = pk2;
            }
            asm volatile("s_waitcnt lgkmcnt(0)" ::: "memory");
            {
                bf16x8 af0 = *(const bf16x8*)(sPw + pr0);
                bf16x8 bg0 = *(const bf16x8*)(sg_lo + cb * 64 + gr0);
                olo = __builtin_amdgcn_mfma_f32_16x16x32_bf16(af0, bg0, olo, 0, 0, 0);
                bf16x8 bh0 = *(const bf16x8*)(sg_hi + cb * 64 + gr0);
                ohi = __builtin_amdgcn_mfma_f32_16x16x32_bf16(af0, bh0, ohi, 0, 0, 0);
                bf16x8 af1 = *(const bf16x8*)(sPw + pr1);
                bf16x8 bg1 = *(const bf16x8*)(sg_lo + cb * 64 + gr1);
                olo = __builtin_amdgcn_mfma_f32_16x16x32_bf16(af1, bg1, olo, 0, 0, 0);
                bf16x8 bh1 = *(const bf16x8*)(sg_hi + cb * 64 + gr1);
                ohi = __builtin_amdgcn_mfma_f32_16x16x32_bf16(af1, bh1, ohi, 0, 0, 0);
            }
        }
        if (t < 3) {
            __syncthreads();                 // all waves done reading tile t
            *(float4*)(&sg[gdst]) = pre;     // swizzled write-back
            __syncthreads();                 // tile t+1 visible
        }
        // t == 3: no barrier — epilogue is wave-local
    }

    // softmax denominator for q = lcol
    ls += __shfl_xor(ls, 16);
    ls += __shfl_xor(ls, 32);
    const float invq = 1.0f / ls;

    // ag (UNNORMALIZED) -> per-wave LDS round-trip: [q][ch], stride 40 (unswizzled; one-shot)
    #pragma unroll
    for (int r = 0; r < 4; ++r) {
        sPw[(quad * 4 + r) * 40 + lcol]      = f2bf(olo[r]);
        sPw[(quad * 4 + r) * 40 + 16 + lcol] = f2bf(ohi[r]);
    }
    asm volatile("s_waitcnt lgkmcnt(0)" ::: "memory");
    bf16x8 agf = *(const bf16x8*)(sPw + lcol * 40 + quad * 8);  // B[k=ch][n=q=lcol]

    const float gmi = gamma[0] * invq;
    const size_t pixbase = ((size_t)b * NPIX + q0w + lcol) * 64;
    #pragma unroll
    for (int ct = 0; ct < 4; ++ct) {
        bf16x8 wa = *(const bf16x8*)(woT_bf + (ct * 16 + lcol) * 32 + quad * 8);
        f32x4 oc = __builtin_amdgcn_mfma_f32_16x16x32_bf16(wa, agf, (f32x4)0.0f, 0, 0, 0);
        const float4 xv = *(const float4*)(x + pixbase + ct * 16 + quad * 4);
        float4 ov;
        ov.x = xv.x + gmi * oc[0];
        ov.y = xv.y + gmi * oc[1];
        ov.z = xv.z + gmi * oc[2];
        ov.w = xv.w + gmi * oc[3];
        *(float4*)(out + pixbase + ct * 16 + quad * 4) = ov;
    }
}

extern "C" void kernel_launch(void* const* d_in, const int* in_sizes, int n_in,
                              void* d_out, int out_size, void* d_ws, size_t ws_size,
                              hipStream_t stream) {
    const float* x       = (const float*)d_in[0];
    const float* w_theta = (const float*)d_in[1];
    const float* u_theta = (const float*)d_in[2];
    const float* w_phi   = (const float*)d_in[3];
    const float* u_phi   = (const float*)d_in[4];
    const float* w_g     = (const float*)d_in[5];
    const float* u_g     = (const float*)d_in[6];
    const float* w_o     = (const float*)d_in[7];
    const float* u_o     = (const float*)d_in[8];
    const float* gamma   = (const float*)d_in[9];
    float* out = (float*)d_out;

    unsigned short* u16base  = (unsigned short*)d_ws;
    unsigned short* theta_bf = u16base;                  // 524288
    unsigned short* phi_bf   = u16base + 524288;         // 131072
    unsigned short* gT_bf    = u16base + 655360;         // 524288
    unsigned short* woT_bf   = u16base + 1179648;        // 2048

    conv_all_kernel<<<512, 256, 0, stream>>>(x, w_theta, u_theta, w_phi, u_phi, w_g, u_g,
                                             w_o, u_o, theta_bf, phi_bf, gT_bf, woT_bf);
    attn_kernel<<<256, 1024, 0, stream>>>(theta_bf, phi_bf, gT_bf, woT_bf, x, gamma, out);
}

// Round 11
// 118.956 us; speedup vs baseline: 1.9095x; 1.1071x over previous
//
#include <hip/hip_runtime.h>
#include <hip/hip_bf16.h>
#include <math.h>

// B=16, H=64, W=64, C=64 -> N=4096 pixels/batch, M=1024 pooled cells.
#define NB 16
#define NPIX 4096
#define MPOOL 1024

typedef __attribute__((ext_vector_type(8))) short bf16x8;  // 8 bf16 (4 VGPRs)
typedef __attribute__((ext_vector_type(4))) float f32x4;   // MFMA C/D frag

#define LOG2E 1.44269504088896340736f

__device__ inline unsigned short f2bf(float f) {
    __hip_bfloat16 h = __float2bfloat16(f);
    return *reinterpret_cast<unsigned short*>(&h);
}

#if defined(__has_builtin)
#if __has_builtin(__builtin_amdgcn_cvt_pk_bf16_f32)
#define HAVE_PK_BF16 1
#endif
#if __has_builtin(__builtin_amdgcn_exp2f)
#define EXP2_HW(x) __builtin_amdgcn_exp2f(x)   // bare v_exp_f32 (libm exp2f is multi-inst without fast-math)
#endif
#endif
#ifndef EXP2_HW
#define EXP2_HW(x) exp2f(x)
#endif

__device__ inline unsigned pack_bf16(float a, float b) {
#ifdef HAVE_PK_BF16
    typedef __bf16 bf16v2 __attribute__((ext_vector_type(2)));
    bf16v2 v = __builtin_amdgcn_cvt_pk_bf16_f32(a, b);
    unsigned u;
    __builtin_memcpy(&u, &v, 4);
    return u;
#else
    unsigned ua = __float_as_uint(a) + 0x8000u;
    unsigned ub = __float_as_uint(b) + 0x8000u;
    return __builtin_amdgcn_perm(ua, ub, 0x03020706u);
#endif
}

// Workspace layout (u16 elements from start of ws):
//   theta_bf @0        [16*4096*8]   (PRE-SCALED by log2e for exp2-softmax)
//   phi_bf   @524288   [16*1024*8]
//   gT_bf    @655360   [16*32*1024]
//   woT_bf   @1179648  [64*32]       (SN'd w_o, transposed [co][k])

__device__ inline float wave_sum64(float v) {
    #pragma unroll
    for (int off = 32; off >= 1; off >>= 1) v += __shfl_xor(v, off);
    return v;
}

// Wave-local spectral norm (one power-iteration step, matches reference).
template<int D, int COUT>
__device__ float sn_inv_sigma(const float* __restrict__ w, const float* __restrict__ u) {
    const int lane = threadIdx.x & 63;
    float vi = 0.f;
    if (lane < D) {
        #pragma unroll 8
        for (int j = 0; j < COUT; ++j) vi += w[lane * COUT + j] * u[j];
    }
    float nn = wave_sum64(vi * vi);
    vi *= 1.0f / (sqrtf(nn) + 1e-12f);

    float u2 = 0.f;
    #pragma unroll 8
    for (int i = 0; i < D; ++i) {
        float vv = __shfl(vi, i);
        if (lane < COUT) u2 += w[i * COUT + lane] * vv;
    }
    float nn2 = wave_sum64(u2 * u2);
    u2 *= 1.0f / (sqrtf(nn2) + 1e-12f);

    float ti = 0.f;
    #pragma unroll 8
    for (int j = 0; j < COUT; ++j) {
        float uv = __shfl(u2, j);
        if (lane < D) ti += w[lane * COUT + j] * uv;
    }
    float sig = wave_sum64(vi * ti);
    return 1.0f / sig;
}

// ---------------- fused SN + conv (byte-identical to verified round-3/6 kernel) ----------------
__global__ __launch_bounds__(256) void conv_all_kernel(const float* __restrict__ x,
                                                       const float* __restrict__ w_theta, const float* __restrict__ u_theta,
                                                       const float* __restrict__ w_phi,   const float* __restrict__ u_phi,
                                                       const float* __restrict__ w_g,     const float* __restrict__ u_g,
                                                       const float* __restrict__ w_o,     const float* __restrict__ u_o,
                                                       unsigned short* __restrict__ theta_bf,
                                                       unsigned short* __restrict__ phi_bf,
                                                       unsigned short* __restrict__ gT_bf,
                                                       unsigned short* __restrict__ woT_bf) {
    __shared__ unsigned short sx[128 * 72];
    __shared__ unsigned short sw[48 * 72];
    __shared__ float s_inv[3];

    const int tid  = threadIdx.x;
    const int b    = blockIdx.x >> 5;
    const int hp   = blockIdx.x & 31;
    const int h0   = hp * 2;
    const int wv   = tid >> 6;
    const int lane = tid & 63;
    const int quad = lane >> 4;
    const int lcol = lane & 15;
    const int w0   = wv * 16;

    const float4* xb4 = (const float4*)(x + (((size_t)b * NPIX) + h0 * 64) * 64);
    #pragma unroll
    for (int it = 0; it < 8; ++it) {
        const int li = tid + it * 256;
        float4 v = xb4[li];
        const int px = li >> 4, c4 = li & 15;
        uint2 pk;
        pk.x = pack_bf16(v.x, v.y);
        pk.y = pack_bf16(v.z, v.w);
        *(uint2*)(&sx[px * 72 + c4 * 4]) = pk;
    }
    if (wv == 0)      { float iv = sn_inv_sigma<64, 8>(w_theta, u_theta); if (lane == 0) s_inv[0] = iv; }
    else if (wv == 1) { float iv = sn_inv_sigma<64, 8>(w_phi,   u_phi);   if (lane == 0) s_inv[1] = iv; }
    else if (wv == 2) { float iv = sn_inv_sigma<64, 32>(w_g,    u_g);     if (lane == 0) s_inv[2] = iv; }
    else if (blockIdx.x == 0) {
        float iv = sn_inv_sigma<32, 64>(w_o, u_o);
        for (int idx = lane; idx < 64 * 32; idx += 64) {
            const int n = idx >> 5, k = idx & 31;
            woT_bf[idx] = f2bf(w_o[k * 64 + n] * iv);
        }
    }
    __syncthreads();

    {
        const float i0 = s_inv[0], i1 = s_inv[1], i2 = s_inv[2];
        #pragma unroll
        for (int it = 0; it < 12; ++it) {
            const int idx = tid + it * 256;
            const int col = idx >> 6, k = idx & 63;
            float wvf, inv;
            if (col < 8)       { wvf = w_theta[k * 8 + col];        inv = i0; }
            else if (col < 16) { wvf = w_phi[k * 8 + (col - 8)];    inv = i1; }
            else               { wvf = w_g[k * 32 + (col - 16)];    inv = i2; }
            sw[col * 72 + k] = f2bf(wvf * inv);
        }
    }
    __syncthreads();

    bf16x8 a[2][2];
    #pragma unroll
    for (int hh = 0; hh < 2; ++hh)
        #pragma unroll
        for (int kc = 0; kc < 2; ++kc)
            a[hh][kc] = *(const bf16x8*)(sx + (hh * 64 + w0 + lcol) * 72 + kc * 32 + quad * 8);

    f32x4 acc[2][3];
    #pragma unroll
    for (int ct = 0; ct < 3; ++ct) {
        bf16x8 b0 = *(const bf16x8*)(sw + (ct * 16 + lcol) * 72 + 0 * 32 + quad * 8);
        bf16x8 b1 = *(const bf16x8*)(sw + (ct * 16 + lcol) * 72 + 1 * 32 + quad * 8);
        #pragma unroll
        for (int hh = 0; hh < 2; ++hh) {
            f32x4 c = __builtin_amdgcn_mfma_f32_16x16x32_bf16(a[hh][0], b0, (f32x4)0.0f, 0, 0, 0);
            acc[hh][ct] = __builtin_amdgcn_mfma_f32_16x16x32_bf16(a[hh][1], b1, c, 0, 0, 0);
        }
    }
    __syncthreads();

    unsigned short* th = sx;
    unsigned short* ph = sx + 1024;
    unsigned short* gg = sx + 1280;
    const int ml = (w0 >> 1) + quad * 2;
    if (lcol < 8) {
        #pragma unroll
        for (int hh = 0; hh < 2; ++hh) {
            const int pix = hh * 64 + w0 + quad * 4;
            #pragma unroll
            for (int r = 0; r < 4; ++r)
                th[(pix + r) * 8 + lcol] = f2bf(acc[hh][0][r] * LOG2E);
        }
    } else {
        #pragma unroll
        for (int r2 = 0; r2 < 2; ++r2) {
            float pe = fmaxf(fmaxf(acc[0][0][2 * r2], acc[0][0][2 * r2 + 1]),
                             fmaxf(acc[1][0][2 * r2], acc[1][0][2 * r2 + 1]));
            ph[(ml + r2) * 8 + (lcol - 8)] = f2bf(pe);
        }
    }
    #pragma unroll
    for (int ct = 1; ct < 3; ++ct) {
        const int cg = (ct - 1) * 16 + lcol;
        #pragma unroll
        for (int r2 = 0; r2 < 2; ++r2) {
            float pe = fmaxf(fmaxf(acc[0][ct][2 * r2], acc[0][ct][2 * r2 + 1]),
                             fmaxf(acc[1][ct][2 * r2], acc[1][ct][2 * r2 + 1]));
            gg[cg * 32 + ml + r2] = f2bf(pe);
        }
    }
    __syncthreads();

    const float4* sv4 = (const float4*)sx;
    float4* th4 = (float4*)(theta_bf + ((size_t)b * NPIX + hp * 128) * 8);
    float4* ph4 = (float4*)(phi_bf + ((size_t)b * MPOOL + hp * 32) * 8);
    for (int idx = tid; idx < 288; idx += 256) {
        float4 v = sv4[idx];
        if (idx < 128) {
            th4[idx] = v;
        } else if (idx < 160) {
            ph4[idx - 128] = v;
        } else {
            const int gi = idx - 160;
            const int ch = gi >> 2, part = gi & 3;
            *(float4*)(gT_bf + ((size_t)b * 32 + ch) * MPOOL + hp * 32 + part * 8) = v;
        }
    }
}

// ---------------- attn v5: EXACT round-6 structure, single change = bare v_exp_f32 ----------------
// A/B vs R6 (120.1): only exp2f -> __builtin_amdgcn_exp2f. R10's swizzle/offset bundle
// is reverted (bank re-derivation: original stride-72 layout already spreads b128 reads
// uniformly; XOR key into an additive bank function concentrated them -> the regression).
__global__ __launch_bounds__(1024) void attn_kernel(const unsigned short* __restrict__ theta_bf,
                                                    const unsigned short* __restrict__ phi_bf,
                                                    const unsigned short* __restrict__ gT_bf,
                                                    const unsigned short* __restrict__ woT_bf,
                                                    const float* __restrict__ x,
                                                    const float* __restrict__ gamma,
                                                    float* __restrict__ out) {
    __shared__ unsigned short sphi[MPOOL * 8];    // 16 KB
    __shared__ unsigned short sg[32 * 264];       // 16.9 KB: gT tile [32 ch][256 m + 8 pad]
    __shared__ unsigned short sP[16][16 * 72];    // 36.9 KB: per-wave P 16q x 64m, stride 72

    const int tid  = threadIdx.x;
    const int b    = blockIdx.x >> 4;
    const int qb   = blockIdx.x & 15;
    const int w    = tid >> 6;                    // wave 0..15
    const int lane = tid & 63;
    const int quad = lane >> 4;
    const int lcol = lane & 15;

    // stage phi[b] (16 KB): 1024 float4, one per thread
    {
        const float4* src = (const float4*)(phi_bf + (size_t)b * (MPOOL * 8));
        ((float4*)sphi)[tid] = src[tid];
    }
    // stage gT tile 0: thread (r=tid>>5, seg=tid&31) copies m seg*8..+7 (one float4)
    const unsigned short* gTb = gT_bf + (size_t)b * (32 * MPOOL);
    const int gr = tid >> 5, gseg = tid & 31;
    {
        *(float4*)(&sg[gr * 264 + gseg * 8]) =
            *(const float4*)(gTb + gr * MPOOL + gseg * 8);
    }
    // theta frag (K=8 real, zero-pad k>=8 -> quads 1-3 zero); used as B operand.
    const int q0w = qb * 256 + w * 16;
    bf16x8 tfrag = (bf16x8)(short)0;
    if (quad == 0)
        tfrag = *(const bf16x8*)(theta_bf + ((size_t)b * NPIX + q0w + lcol) * 8);
    __syncthreads();

    f32x4 olo = (f32x4)0.0f, ohi = (f32x4)0.0f;
    float ls = 0.f;
    unsigned short* sPw = sP[w];

    for (int t = 0; t < 4; ++t) {
        float4 pre;
        if (t < 3)
            pre = *(const float4*)(gTb + gr * MPOOL + (t + 1) * 256 + gseg * 8);
        for (int cb = 0; cb < 4; ++cb) {
            const int m0 = t * 256 + cb * 64;
            f32x4 s[4];
            #pragma unroll
            for (int sc = 0; sc < 4; ++sc) {
                bf16x8 pf = *(const bf16x8*)(sphi + (size_t)(m0 + sc * 16 + lcol) * 8);
                // S^T tile: D[row=m (quad*4+r within sc*16)][col=q (lcol)]
                s[sc] = __builtin_amdgcn_mfma_f32_16x16x32_bf16(pf, tfrag, (f32x4)0.0f, 0, 0, 0);
            }
            #pragma unroll
            for (int sc = 0; sc < 4; ++sc) {
                float e0 = EXP2_HW(s[sc][0]);
                float e1 = EXP2_HW(s[sc][1]);
                float e2 = EXP2_HW(s[sc][2]);
                float e3 = EXP2_HW(s[sc][3]);
                ls += (e0 + e1) + (e2 + e3);
                uint2 pk2;
                pk2.x = pack_bf16(e0, e1);
                pk2.y = pack_bf16(e2, e3);
                *(uint2*)(sPw + lcol * 72 + sc * 16 + quad * 4) = pk2;
            }
            asm volatile("s_waitcnt lgkmcnt(0)" ::: "memory");
            #pragma unroll
            for (int pkk = 0; pkk < 2; ++pkk) {
                bf16x8 afrag = *(const bf16x8*)(sPw + lcol * 72 + pkk * 32 + quad * 8);
                bf16x8 bg0 = *(const bf16x8*)(sg + lcol * 264 + cb * 64 + pkk * 32 + quad * 8);
                olo = __builtin_amdgcn_mfma_f32_16x16x32_bf16(afrag, bg0, olo, 0, 0, 0);
                bf16x8 bg1 = *(const bf16x8*)(sg + (16 + lcol) * 264 + cb * 64 + pkk * 32 + quad * 8);
                ohi = __builtin_amdgcn_mfma_f32_16x16x32_bf16(afrag, bg1, ohi, 0, 0, 0);
            }
        }
        if (t < 3) {
            __syncthreads();   // all waves done reading tile t
            *(float4*)(&sg[gr * 264 + gseg * 8]) = pre;
            __syncthreads();   // tile t+1 visible
        }
        // t == 3: no barrier — epilogue is wave-local, waves drain independently
    }

    // softmax denominator for q = lcol: sum over quads (lanes lcol+16k)
    ls += __shfl_xor(ls, 16);
    ls += __shfl_xor(ls, 32);
    const float invq = 1.0f / ls;

    // ag (UNNORMALIZED) -> per-wave LDS round-trip: [q][ch], stride 40
    #pragma unroll
    for (int r = 0; r < 4; ++r) {
        sPw[(quad * 4 + r) * 40 + lcol]      = f2bf(olo[r]);
        sPw[(quad * 4 + r) * 40 + 16 + lcol] = f2bf(ohi[r]);
    }
    asm volatile("s_waitcnt lgkmcnt(0)" ::: "memory");
    bf16x8 agf = *(const bf16x8*)(sPw + lcol * 40 + quad * 8);  // B[k=ch][n=q=lcol]

    const float gmi = gamma[0] * invq;
    const size_t pixbase = ((size_t)b * NPIX + q0w + lcol) * 64;
    #pragma unroll
    for (int ct = 0; ct < 4; ++ct) {
        // A[co][k] straight from L2 (woT is 4 KB, shared by all blocks)
        bf16x8 wa = *(const bf16x8*)(woT_bf + (ct * 16 + lcol) * 32 + quad * 8);
        f32x4 oc = __builtin_amdgcn_mfma_f32_16x16x32_bf16(wa, agf, (f32x4)0.0f, 0, 0, 0);
        const float4 xv = *(const float4*)(x + pixbase + ct * 16 + quad * 4);
        float4 ov;
        ov.x = xv.x + gmi * oc[0];
        ov.y = xv.y + gmi * oc[1];
        ov.z = xv.z + gmi * oc[2];
        ov.w = xv.w + gmi * oc[3];
        *(float4*)(out + pixbase + ct * 16 + quad * 4) = ov;
    }
}

extern "C" void kernel_launch(void* const* d_in, const int* in_sizes, int n_in,
                              void* d_out, int out_size, void* d_ws, size_t ws_size,
                              hipStream_t stream) {
    const float* x       = (const float*)d_in[0];
    const float* w_theta = (const float*)d_in[1];
    const float* u_theta = (const float*)d_in[2];
    const float* w_phi   = (const float*)d_in[3];
    const float* u_phi   = (const float*)d_in[4];
    const float* w_g     = (const float*)d_in[5];
    const float* u_g     = (const float*)d_in[6];
    const float* w_o     = (const float*)d_in[7];
    const float* u_o     = (const float*)d_in[8];
    const float* gamma   = (const float*)d_in[9];
    float* out = (float*)d_out;

    unsigned short* u16base  = (unsigned short*)d_ws;
    unsigned short* theta_bf = u16base;                  // 524288
    unsigned short* phi_bf   = u16base + 524288;         // 131072
    unsigned short* gT_bf    = u16base + 655360;         // 524288
    unsigned short* woT_bf   = u16base + 1179648;        // 2048

    conv_all_kernel<<<512, 256, 0, stream>>>(x, w_theta, u_theta, w_phi, u_phi, w_g, u_g,
                                             w_o, u_o, theta_bf, phi_bf, gT_bf, woT_bf);
    attn_kernel<<<256, 1024, 0, stream>>>(theta_bf, phi_bf, gT_bf, woT_bf, x, gamma, out);
}